// Round 2
// baseline (354.412 us; speedup 1.0000x reference)
//
#include <hip/hip_runtime.h>
#include <math.h>

#define KSEL 15
#define CIN 128
#define CF 16
#define HH 112
#define NN 256          // nodes per patch (16x16)
#define GRIDW 7         // W_SIZE

__global__ __launch_bounds__(256) void gnn_patch_kernel(
    const float* __restrict__ x,
    const float* __restrict__ fw,
    const float* __restrict__ fb,
    const float* __restrict__ ea,
    const float* __restrict__ eb,
    float* __restrict__ out)
{
    __shared__ double lfw[CIN * CF];   // f_w transposed: [c][d]  (16 KB)
    __shared__ double lfb[CF];
    __shared__ double xa[NN * 18];     // normalized augmented features (36 KB), rows 16B-aligned
    __shared__ float  xpl[NN * 4];     // staging: 4 c-planes, layout [pos*4 + plane] (4 KB)

    const int t  = threadIdx.x;       // node index n within patch
    const int p  = blockIdx.x;        // patch index
    const int b  = p / (GRIDW * GRIDW);
    const int g  = p % (GRIDW * GRIDW);
    const int gI = g / GRIDW, gJ = g % GRIDW;
    const int row0 = gI * 16, col0 = gJ * 16;
    const int i = t >> 4, j = t & 15;

    const size_t planeStride = (size_t)HH * HH;
    const float* xbase = x   + (size_t)b * CIN * planeStride + (size_t)(row0 * HH + col0);
    float*       obase = out + (size_t)b * CIN * planeStride + (size_t)(row0 * HH + col0);

    // ---- stage f_w (transposed, fp64) and f_b into LDS ----
    for (int q = t; q < CIN * CF; q += 256) {
        int d = q >> 7, c = q & 127;        // fw is [d][c] row-major
        lfw[c * CF + d] = (double)fw[q];
    }
    if (t < CF) lfb[t] = (double)fb[t];
    __syncthreads();

    // ---- Phase A (fp64): 1x1 conv -> 16 ch, augment grid, L2-normalize ----
    double acc[CF];
#pragma unroll
    for (int d = 0; d < CF; ++d) acc[d] = 0.0;
    const float* xp = xbase + (i * HH + j);
    for (int c = 0; c < CIN; ++c) {
        double xc = (double)xp[(size_t)c * planeStride];
        const double* w = &lfw[c * CF];
#pragma unroll
        for (int d = 0; d < CF; ++d) acc[d] = fma(xc, w[d], acc[d]);
    }
#pragma unroll
    for (int d = 0; d < CF; ++d) acc[d] += lfb[d];

    // grid feature: (coord - 7.5) / (std_ddof1 + 1e-5); std = sqrt(5440/255)
    const double GDIV = 4.618802153517006 + 1e-5;
    double gx = ((double)i - 7.5) / GDIV;
    double gy = ((double)j - 7.5) / GDIV;

    double ss = 0.0;
#pragma unroll
    for (int d = 0; d < CF; ++d) ss = fma(acc[d], acc[d], ss);
    ss = fma(gx, gx, ss);
    ss = fma(gy, gy, ss);
    double nrm = fmax(sqrt(ss), 1e-8);

#pragma unroll
    for (int d = 0; d < CF; ++d) xa[t * 18 + d] = acc[d] / nrm;
    xa[t * 18 + 16] = gx / nrm;
    xa[t * 18 + 17] = gy / nrm;
    __syncthreads();

    // ---- Phase B (fp64): similarity row + top-15 membership ----
    double xr[18];
#pragma unroll
    for (int d = 0; d < 18; ++d) xr[d] = xa[t * 18 + d];

    double tv[KSEL];
    int    tix[KSEL];
#pragma unroll
    for (int k = 0; k < KSEL; ++k) { tv[k] = -2.0; tix[k] = 0; }

    for (int m = 0; m < NN; ++m) {
        const double2* xm = (const double2*)&xa[m * 18];
        double s = 0.0;
#pragma unroll
        for (int d = 0; d < 9; ++d) {
            double2 v2 = xm[d];
            s = fma(xr[2 * d],     v2.x, s);
            s = fma(xr[2 * d + 1], v2.y, s);
        }
        if (s > tv[KSEL - 1]) {
            double v = s; int mi = m;
#pragma unroll
            for (int u = 0; u < KSEL; ++u) {
                bool   gtv = v > tv[u];
                double ov = tv[u]; int oi = tix[u];
                tv[u]  = gtv ? v  : ov;
                tix[u] = gtv ? mi : oi;
                v  = gtv ? ov : v;
                mi = gtv ? oi : mi;
            }
        }
    }

    // ---- Phase C (fp64): softmax_k(sigmoid(beta + alpha * topv)) ----
    double alpha = (double)ea[0], beta = (double)eb[0];
    double wkd[KSEL];
    double mx = -1e300;
#pragma unroll
    for (int k = 0; k < KSEL; ++k) {
        double sg = 1.0 / (1.0 + exp(-(beta + alpha * tv[k])));
        wkd[k] = sg;
        mx = fmax(mx, sg);
    }
    double se = 0.0;
#pragma unroll
    for (int k = 0; k < KSEL; ++k) { wkd[k] = exp(wkd[k] - mx); se += wkd[k]; }
    float wk[KSEL];
#pragma unroll
    for (int k = 0; k < KSEL; ++k) wk[k] = (float)(wkd[k] / se);

    // ---- Phase D (fp32): gather original 128-ch features of top-15 neighbors ----
    const int spl = t & 3;
    const int sp0 = (t >> 2) * 4;
    const int si = sp0 >> 4, sj = sp0 & 15;

    for (int c0 = 0; c0 < CIN; c0 += 4) {
        __syncthreads();   // previous iteration's reads done before overwrite
        const float* src = xbase + (size_t)(c0 + spl) * planeStride + (si * HH + sj);
        float4 v4 = *(const float4*)src;   // 16B-aligned
        xpl[(sp0 + 0) * 4 + spl] = v4.x;
        xpl[(sp0 + 1) * 4 + spl] = v4.y;
        xpl[(sp0 + 2) * 4 + spl] = v4.z;
        xpl[(sp0 + 3) * 4 + spl] = v4.w;
        __syncthreads();

        float o0 = 0.f, o1 = 0.f, o2 = 0.f, o3 = 0.f;
#pragma unroll
        for (int k = 0; k < KSEL; ++k) {
            float w = wk[k];
            const float4 xv = *(const float4*)&xpl[tix[k] * 4];
            o0 = fmaf(w, xv.x, o0);
            o1 = fmaf(w, xv.y, o1);
            o2 = fmaf(w, xv.z, o2);
            o3 = fmaf(w, xv.w, o3);
        }
        float* dst = obase + (size_t)c0 * planeStride + (i * HH + j);
        dst[0 * planeStride] = o0;
        dst[1 * planeStride] = o1;
        dst[2 * planeStride] = o2;
        dst[3 * planeStride] = o3;
    }
}

extern "C" void kernel_launch(void* const* d_in, const int* in_sizes, int n_in,
                              void* d_out, int out_size, void* d_ws, size_t ws_size,
                              hipStream_t stream) {
    const float* x  = (const float*)d_in[0];
    const float* fw = (const float*)d_in[1];
    const float* fb = (const float*)d_in[2];
    const float* ea = (const float*)d_in[3];
    const float* eb = (const float*)d_in[4];
    float* out = (float*)d_out;

    int nB = in_sizes[0] / (CIN * HH * HH);   // 4
    int nBlocks = nB * GRIDW * GRIDW;         // 196

    hipLaunchKernelGGL(gnn_patch_kernel, dim3(nBlocks), dim3(256), 0, stream,
                       x, fw, fb, ea, eb, out);
}

// Round 3
// 171.195 us; speedup vs baseline: 2.0702x; 2.0702x over previous
//
#include <hip/hip_runtime.h>
#include <math.h>

#define KSEL 15
#define CIN 128
#define CF 16
#define HH 112
#define PLANE 12544      // 112*112
#define NN 256
#define GRIDW 7
#define ROWSTRIDE 20     // padded feature row (18 used)

static __device__ __forceinline__ unsigned mono32(float f) {
    unsigned u = __float_as_uint(f);
    return ((int)u < 0) ? ~u : (u | 0x80000000u);
}
static __device__ __forceinline__ float demono32(unsigned u) {
    return ((int)u < 0) ? __uint_as_float(u & 0x7FFFFFFFu) : __uint_as_float(~u);
}
static __device__ __forceinline__ unsigned long long mono64(double f) {
    unsigned long long u = (unsigned long long)__double_as_longlong(f);
    return ((long long)u < 0) ? ~u : (u | 0x8000000000000000ull);
}

// ---------------- K1: features (fp64 conv -> augment -> normalize) ----------------
__global__ __launch_bounds__(256) void k1_features(
    const float* __restrict__ x, const float* __restrict__ fw, const float* __restrict__ fb,
    double* __restrict__ xa64, float* __restrict__ xa32)
{
    __shared__ float lfw[CIN * CF];   // [c][d]
    __shared__ float lfb[CF];
    const int tid = threadIdx.x;
    const int p  = blockIdx.x >> 2;
    const int n0 = (blockIdx.x & 3) * 64;
    const int b = p / 49, g = p % 49;
    const int gI = g / 7, gJ = g % 7;
    const float* xb = x + (size_t)b * CIN * PLANE + (size_t)(gI * 16 * HH + gJ * 16);

    for (int q = tid; q < CIN * CF; q += 256) { int d = q >> 7, c = q & 127; lfw[c * CF + d] = fw[q]; }
    if (tid < CF) lfb[tid] = fb[tid];
    __syncthreads();

    const int nl = tid >> 2, dq = tid & 3;
    const int n = n0 + nl, i = n >> 4, j = n & 15;
    const float* xp = xb + i * HH + j;

    double a0 = 0.0, a1 = 0.0, a2 = 0.0, a3 = 0.0;
#pragma unroll 4
    for (int c = 0; c < CIN; ++c) {
        double xc = (double)xp[(size_t)c * PLANE];
        float4 wv = *(const float4*)&lfw[c * CF + dq * 4];
        a0 = fma(xc, (double)wv.x, a0);
        a1 = fma(xc, (double)wv.y, a1);
        a2 = fma(xc, (double)wv.z, a2);
        a3 = fma(xc, (double)wv.w, a3);
    }
    a0 += (double)lfb[dq * 4 + 0];
    a1 += (double)lfb[dq * 4 + 1];
    a2 += (double)lfb[dq * 4 + 2];
    a3 += (double)lfb[dq * 4 + 3];

    const double GDIV = 4.618802153517006 + 1e-5;
    double gx = ((double)i - 7.5) / GDIV;
    double gy = ((double)j - 7.5) / GDIV;

    double ss = a0 * a0;
    ss = fma(a1, a1, ss); ss = fma(a2, a2, ss); ss = fma(a3, a3, ss);
    if (dq == 3) { ss = fma(gx, gx, ss); ss = fma(gy, gy, ss); }
    ss += __shfl_xor(ss, 1);
    ss += __shfl_xor(ss, 2);
    double nrm = fmax(sqrt(ss), 1e-8);

    size_t ro = ((size_t)p * NN + n) * ROWSTRIDE;
    double o0 = a0 / nrm, o1 = a1 / nrm, o2 = a2 / nrm, o3 = a3 / nrm;
    xa64[ro + dq * 4 + 0] = o0; xa64[ro + dq * 4 + 1] = o1;
    xa64[ro + dq * 4 + 2] = o2; xa64[ro + dq * 4 + 3] = o3;
    xa32[ro + dq * 4 + 0] = (float)o0; xa32[ro + dq * 4 + 1] = (float)o1;
    xa32[ro + dq * 4 + 2] = (float)o2; xa32[ro + dq * 4 + 3] = (float)o3;
    if (dq == 3) {
        double g0 = gx / nrm, g1 = gy / nrm;
        xa64[ro + 16] = g0; xa64[ro + 17] = g1; xa64[ro + 18] = 0.0; xa64[ro + 19] = 0.0;
        xa32[ro + 16] = (float)g0; xa32[ro + 17] = (float)g1; xa32[ro + 18] = 0.f; xa32[ro + 19] = 0.f;
    }
}

// ---------------- K2: fp32 sims + packed-key top-16 + fp64 refine + weights ----------------
__global__ __launch_bounds__(256) void k2_select(
    const double* __restrict__ xa64, const float* __restrict__ xa32,
    const float* __restrict__ ea, const float* __restrict__ eb,
    int* __restrict__ topi, float* __restrict__ wkout, unsigned* __restrict__ flags)
{
    __shared__ float tile[NN * ROWSTRIDE];    // 20 KB
    __shared__ unsigned kv[NN * 17];          // 17 KB, per-thread sorted key lists
    const int tid = threadIdx.x;
    const int p = blockIdx.x >> 4, sub = blockIdx.x & 15;

    const float* src = xa32 + (size_t)p * NN * ROWSTRIDE;
#pragma unroll
    for (int q = 0; q < 5; ++q) {
        int idx = q * 256 + tid;
        ((float4*)tile)[idx] = ((const float4*)src)[idx];
    }
    __syncthreads();

    const int lane = tid & 15;
    const int grp  = tid >> 4;                 // 0..15 row-in-block
    const int rip  = sub * 16 + grp;           // row in patch
    const int row  = p * NN + rip;

    float xr[18];
#pragma unroll
    for (int d = 0; d < 18; ++d) xr[d] = tile[rip * ROWSTRIDE + d];

    unsigned k[16];
#pragma unroll
    for (int s = 0; s < 16; ++s) {
        int m = s * 16 + lane;
        const float* xm = &tile[m * ROWSTRIDE];
        float acc = 0.f;
#pragma unroll
        for (int d = 0; d < 18; ++d) acc = fmaf(xr[d], xm[d], acc);
        k[s] = (mono32(acc) & 0xFFFFFF00u) | (unsigned)(255 - m);
    }

    // bitonic sort ascending (registers, fully unrolled)
#pragma unroll
    for (int kk = 2; kk <= 16; kk <<= 1) {
#pragma unroll
        for (int jj = kk >> 1; jj > 0; jj >>= 1) {
#pragma unroll
            for (int ii = 0; ii < 16; ++ii) {
                int ll = ii ^ jj;
                if (ll > ii) {
                    bool up = ((ii & kk) == 0);
                    unsigned a = k[ii], bb = k[ll];
                    bool sw = up ? (a > bb) : (a < bb);
                    k[ii] = sw ? bb : a; k[ll] = sw ? a : bb;
                }
            }
        }
    }
#pragma unroll
    for (int s = 0; s < 16; ++s) kv[tid * 17 + s] = k[s];  // own-list only, no sync needed

    int ptr = 15;
    unsigned mycand = 0;
    unsigned myhead = k[15];
#pragma unroll
    for (int e = 0; e < 16; ++e) {
        unsigned W = myhead;
        unsigned o;
        o = __shfl_xor(W, 1);  W = (o > W) ? o : W;
        o = __shfl_xor(W, 2);  W = (o > W) ? o : W;
        o = __shfl_xor(W, 4);  W = (o > W) ? o : W;
        o = __shfl_xor(W, 8);  W = (o > W) ? o : W;
        if (lane == e) mycand = W;
        bool won = (myhead == W);
        ptr -= won ? 1 : 0;
        int rp = ptr < 0 ? 0 : ptr;
        unsigned reread = kv[tid * 17 + rp];
        myhead = won ? reread : myhead;
    }

    // certification
    unsigned v15 = __shfl(mycand, 14, 16);
    unsigned v16 = __shfl(mycand, 15, 16);
    float lo = demono32(v15 & 0xFFFFFF00u) - 1e-5f;
    float hi = demono32((v16 & 0xFFFFFF00u) + 0x100u) + 1e-5f;
    bool dirty = !(hi < lo);
    if (lane == 0) flags[row] = dirty ? 1u : 0u;

    // fp64 refine of the 16 candidates (lane l holds candidate #l)
    int mym = 255 - (int)(mycand & 0xFFu);
    const double* xr64 = xa64 + (size_t)row * ROWSTRIDE;
    const double* xm64 = xa64 + ((size_t)p * NN + mym) * ROWSTRIDE;
    double s64 = 0.0;
#pragma unroll
    for (int d = 0; d < 18; ++d) s64 = fma(xr64[d], xm64[d], s64);

    unsigned long long rkey = (mono64(s64) & ~0xFFull) | (unsigned long long)(255 - mym);
    unsigned long long rmin = rkey, ro_;
    ro_ = __shfl_xor(rmin, 1);  rmin = (ro_ < rmin) ? ro_ : rmin;
    ro_ = __shfl_xor(rmin, 2);  rmin = (ro_ < rmin) ? ro_ : rmin;
    ro_ = __shfl_xor(rmin, 4);  rmin = (ro_ < rmin) ? ro_ : rmin;
    ro_ = __shfl_xor(rmin, 8);  rmin = (ro_ < rmin) ? ro_ : rmin;
    bool loser = (rkey == rmin);

    float alpha = ea[0], beta = eb[0];
    float sg = 1.f / (1.f + expf(-(beta + alpha * (float)s64)));
    float v = loser ? -1e30f : sg;
    float mx = v, of;
    of = __shfl_xor(mx, 1); mx = fmaxf(mx, of);
    of = __shfl_xor(mx, 2); mx = fmaxf(mx, of);
    of = __shfl_xor(mx, 4); mx = fmaxf(mx, of);
    of = __shfl_xor(mx, 8); mx = fmaxf(mx, of);
    float ex = expf(v - mx);
    float sm = ex;
    of = __shfl_xor(sm, 1); sm += of;
    of = __shfl_xor(sm, 2); sm += of;
    of = __shfl_xor(sm, 4); sm += of;
    of = __shfl_xor(sm, 8); sm += of;
    float w = ex / sm;

    topi[row * 16 + lane] = mym;
    wkout[row * 16 + lane] = w;
}

// ---------------- K2b: exact fp64 redo for dirty rows (wave per row) ----------------
__global__ __launch_bounds__(64) void k2b_dirty(
    const double* __restrict__ xa64, const float* __restrict__ ea, const float* __restrict__ eb,
    const unsigned* __restrict__ flags, int* __restrict__ topi, float* __restrict__ wkout)
{
    const int row = blockIdx.x;
    if (flags[row] == 0) return;
    const int lane = threadIdx.x;
    const int p = row >> 8;
    const double* xr64 = xa64 + (size_t)row * ROWSTRIDE;

    double sv[4]; int smi[4];
#pragma unroll
    for (int s4 = 0; s4 < 4; ++s4) {
        int m = s4 * 64 + lane;
        const double* xm64 = xa64 + ((size_t)p * NN + m) * ROWSTRIDE;
        double s = 0.0;
#pragma unroll
        for (int d = 0; d < 18; ++d) s = fma(xr64[d], xm64[d], s);
        sv[s4] = s; smi[s4] = m;
    }

    double cv = -3.0; int cm = 0;
#pragma unroll
    for (int e = 0; e < KSEL; ++e) {
        double lv = sv[0]; int lm = smi[0];
#pragma unroll
        for (int s4 = 1; s4 < 4; ++s4) {
            bool t = (sv[s4] > lv) || (sv[s4] == lv && smi[s4] < lm);
            lv = t ? sv[s4] : lv; lm = t ? smi[s4] : lm;
        }
#pragma unroll
        for (int off = 1; off < 64; off <<= 1) {
            double ov = __shfl_xor(lv, off);
            int    om = __shfl_xor(lm, off);
            bool t = (ov > lv) || (ov == lv && om < lm);
            lv = t ? ov : lv; lm = t ? om : lm;
        }
        if (lane == e) { cv = lv; cm = lm; }
#pragma unroll
        for (int s4 = 0; s4 < 4; ++s4) if (smi[s4] == lm) sv[s4] = -3.0;
    }

    float alpha = ea[0], beta = eb[0];
    float sg = 1.f / (1.f + expf(-(beta + alpha * (float)cv)));
    float v = (lane < KSEL) ? sg : -1e30f;
    float mx = v, of;
    for (int off = 1; off < 64; off <<= 1) { of = __shfl_xor(mx, off); mx = fmaxf(mx, of); }
    float ex = expf(v - mx);
    float sm = ex;
    for (int off = 1; off < 64; off <<= 1) { of = __shfl_xor(sm, off); sm += of; }
    float w = ex / sm;
    if (lane < 16) {
        topi[row * 16 + lane] = (lane < KSEL) ? cm : 0;
        wkout[row * 16 + lane] = (lane < KSEL) ? w : 0.f;
    }
}

// ---------------- K3: weighted gather-aggregate ----------------
__global__ __launch_bounds__(256) void k3_aggregate(
    const float* __restrict__ x, const int* __restrict__ topi, const float* __restrict__ wk,
    float* __restrict__ out)
{
    __shared__ float tile[NN * ROWSTRIDE];   // [pos][20], 16 channels used
    const int tid = threadIdx.x;
    const int pb = blockIdx.x >> 3, cg = blockIdx.x & 7, c0 = cg * 16;
    const int b = pb / 49, g = pb % 49;
    const int gI = g / 7, gJ = g % 7;
    const float* xb = x + ((size_t)b * CIN + c0) * PLANE + (size_t)(gI * 16 * HH + gJ * 16);

#pragma unroll
    for (int rep = 0; rep < 4; ++rep) {
        int linear = rep * 256 + tid;
        int cc = linear >> 6, chunk = linear & 63;
        int pos = chunk * 4, ii = pos >> 4, jj = pos & 15;
        float4 v = *(const float4*)(xb + (size_t)cc * PLANE + ii * HH + jj);
        tile[(pos + 0) * ROWSTRIDE + cc] = v.x;
        tile[(pos + 1) * ROWSTRIDE + cc] = v.y;
        tile[(pos + 2) * ROWSTRIDE + cc] = v.z;
        tile[(pos + 3) * ROWSTRIDE + cc] = v.w;
    }
    __syncthreads();

    const int n = tid;
    const int row = pb * NN + n;
    float acc[16];
#pragma unroll
    for (int c = 0; c < 16; ++c) acc[c] = 0.f;

#pragma unroll
    for (int kq = 0; kq < 4; ++kq) {
        int4   mi4 = ((const int4*)(topi + (size_t)row * 16))[kq];
        float4 w4  = ((const float4*)(wk  + (size_t)row * 16))[kq];
        const int   mis[4] = { mi4.x, mi4.y, mi4.z, mi4.w };
        const float ws4[4] = { w4.x, w4.y, w4.z, w4.w };
#pragma unroll
        for (int u = 0; u < 4; ++u) {
            float w = ws4[u];
            const float4* sp = (const float4*)&tile[mis[u] * ROWSTRIDE];
#pragma unroll
            for (int q = 0; q < 4; ++q) {
                float4 f = sp[q];
                acc[q * 4 + 0] = fmaf(w, f.x, acc[q * 4 + 0]);
                acc[q * 4 + 1] = fmaf(w, f.y, acc[q * 4 + 1]);
                acc[q * 4 + 2] = fmaf(w, f.z, acc[q * 4 + 2]);
                acc[q * 4 + 3] = fmaf(w, f.w, acc[q * 4 + 3]);
            }
        }
    }
    const int ii = n >> 4, jj = n & 15;
    float* ob = out + ((size_t)b * CIN + c0) * PLANE + (size_t)(gI * 16 * HH + gJ * 16) + ii * HH + jj;
#pragma unroll
    for (int cc = 0; cc < 16; ++cc) ob[(size_t)cc * PLANE] = acc[cc];
}

extern "C" void kernel_launch(void* const* d_in, const int* in_sizes, int n_in,
                              void* d_out, int out_size, void* d_ws, size_t ws_size,
                              hipStream_t stream) {
    const float* x  = (const float*)d_in[0];
    const float* fw = (const float*)d_in[1];
    const float* fb = (const float*)d_in[2];
    const float* ea = (const float*)d_in[3];
    const float* eb = (const float*)d_in[4];
    float* out = (float*)d_out;

    int nB = in_sizes[0] / (CIN * PLANE);   // 4
    int nP = nB * 49;                       // 196
    size_t nRows = (size_t)nP * NN;         // 50176

    char* wsb = (char*)d_ws;
    size_t off = 0;
    auto carve = [&](size_t bytes) { char* r = wsb + off; off = (off + bytes + 255) & ~(size_t)255; return r; };
    double*   xa64  = (double*)  carve(nRows * ROWSTRIDE * sizeof(double));
    float*    xa32  = (float*)   carve(nRows * ROWSTRIDE * sizeof(float));
    int*      topi  = (int*)     carve(nRows * 16 * sizeof(int));
    float*    wk    = (float*)   carve(nRows * 16 * sizeof(float));
    unsigned* flags = (unsigned*)carve(nRows * sizeof(unsigned));

    hipLaunchKernelGGL(k1_features, dim3(nP * 4), dim3(256), 0, stream, x, fw, fb, xa64, xa32);
    hipLaunchKernelGGL(k2_select,   dim3(nP * 16), dim3(256), 0, stream, xa64, xa32, ea, eb, topi, wk, flags);
    hipLaunchKernelGGL(k2b_dirty,   dim3((unsigned)nRows), dim3(64), 0, stream, xa64, ea, eb, flags, topi, wk);
    hipLaunchKernelGGL(k3_aggregate, dim3(nP * 8), dim3(256), 0, stream, x, topi, wk, out);
}

// Round 4
// 156.697 us; speedup vs baseline: 2.2618x; 1.0925x over previous
//
#include <hip/hip_runtime.h>
#include <math.h>

#define KSEL 15
#define CIN 128
#define CF 16
#define HH 112
#define PLANE 12544      // 112*112
#define NN 256
#define ROWSTRIDE 20     // padded feature row (18 used)

static __device__ __forceinline__ unsigned mono32(float f) {
    unsigned u = __float_as_uint(f);
    return ((int)u < 0) ? ~u : (u | 0x80000000u);
}
static __device__ __forceinline__ float demono32(unsigned u) {
    return ((int)u < 0) ? __uint_as_float(u & 0x7FFFFFFFu) : __uint_as_float(~u);
}

// ---------------- K1: features (fp64 conv -> augment -> normalize) ----------------
__global__ __launch_bounds__(256) void k1_features(
    const float* __restrict__ x, const float* __restrict__ fw, const float* __restrict__ fb,
    double* __restrict__ xa64, float* __restrict__ xa32, unsigned* __restrict__ dirtyCount)
{
    __shared__ float lfw[CIN * CF];   // [c][d]
    __shared__ float lfb[CF];
    const int tid = threadIdx.x;
    if (blockIdx.x == 0 && tid == 0) *dirtyCount = 0u;
    const int p  = blockIdx.x >> 2;
    const int n0 = (blockIdx.x & 3) * 64;
    const int b = p / 49, g = p % 49;
    const int gI = g / 7, gJ = g % 7;
    const float* xb = x + (size_t)b * CIN * PLANE + (size_t)(gI * 16 * HH + gJ * 16);

    for (int q = tid; q < CIN * CF; q += 256) { int d = q >> 7, c = q & 127; lfw[c * CF + d] = fw[q]; }
    if (tid < CF) lfb[tid] = fb[tid];
    __syncthreads();

    const int nl = tid >> 2, dq = tid & 3;
    const int n = n0 + nl, i = n >> 4, j = n & 15;
    const float* xp = xb + i * HH + j;

    double a0 = 0.0, a1 = 0.0, a2 = 0.0, a3 = 0.0;
#pragma unroll 4
    for (int c = 0; c < CIN; ++c) {
        double xc = (double)xp[(size_t)c * PLANE];
        float4 wv = *(const float4*)&lfw[c * CF + dq * 4];
        a0 = fma(xc, (double)wv.x, a0);
        a1 = fma(xc, (double)wv.y, a1);
        a2 = fma(xc, (double)wv.z, a2);
        a3 = fma(xc, (double)wv.w, a3);
    }
    a0 += (double)lfb[dq * 4 + 0];
    a1 += (double)lfb[dq * 4 + 1];
    a2 += (double)lfb[dq * 4 + 2];
    a3 += (double)lfb[dq * 4 + 3];

    const double GDIV = 4.618802153517006 + 1e-5;
    double gx = ((double)i - 7.5) / GDIV;
    double gy = ((double)j - 7.5) / GDIV;

    double ss = a0 * a0;
    ss = fma(a1, a1, ss); ss = fma(a2, a2, ss); ss = fma(a3, a3, ss);
    if (dq == 3) { ss = fma(gx, gx, ss); ss = fma(gy, gy, ss); }
    ss += __shfl_xor(ss, 1);
    ss += __shfl_xor(ss, 2);
    double nrm = fmax(sqrt(ss), 1e-8);

    size_t ro = ((size_t)p * NN + n) * ROWSTRIDE;
    double o0 = a0 / nrm, o1 = a1 / nrm, o2 = a2 / nrm, o3 = a3 / nrm;
    xa64[ro + dq * 4 + 0] = o0; xa64[ro + dq * 4 + 1] = o1;
    xa64[ro + dq * 4 + 2] = o2; xa64[ro + dq * 4 + 3] = o3;
    xa32[ro + dq * 4 + 0] = (float)o0; xa32[ro + dq * 4 + 1] = (float)o1;
    xa32[ro + dq * 4 + 2] = (float)o2; xa32[ro + dq * 4 + 3] = (float)o3;
    if (dq == 3) {
        double g0 = gx / nrm, g1 = gy / nrm;
        xa64[ro + 16] = g0; xa64[ro + 17] = g1; xa64[ro + 18] = 0.0; xa64[ro + 19] = 0.0;
        xa32[ro + 16] = (float)g0; xa32[ro + 17] = (float)g1; xa32[ro + 18] = 0.f; xa32[ro + 19] = 0.f;
    }
}

// ---------------- K2: fp32 sims + packed-key top-16 + certification + weights ----------------
__global__ __launch_bounds__(256) void k2_select(
    const float* __restrict__ xa32,
    const float* __restrict__ ea, const float* __restrict__ eb,
    int* __restrict__ topi, float* __restrict__ wkout,
    unsigned* __restrict__ dirtyCount, int* __restrict__ dirtyList)
{
    __shared__ float tile[NN * ROWSTRIDE];    // 20 KB
    __shared__ unsigned kv[NN * 17];          // 17 KB, per-thread sorted key lists
    const int tid = threadIdx.x;
    const int p = blockIdx.x >> 4, sub = blockIdx.x & 15;

    const float* src = xa32 + (size_t)p * NN * ROWSTRIDE;
#pragma unroll
    for (int q = 0; q < 5; ++q) {
        int idx = q * 256 + tid;
        ((float4*)tile)[idx] = ((const float4*)src)[idx];
    }
    __syncthreads();

    const int lane = tid & 15;
    const int grp  = tid >> 4;                 // 0..15 row-in-block
    const int rip  = sub * 16 + grp;           // row in patch
    const int row  = p * NN + rip;

    float xr[18];
#pragma unroll
    for (int d = 0; d < 18; ++d) xr[d] = tile[rip * ROWSTRIDE + d];

    unsigned k[16];
#pragma unroll
    for (int s = 0; s < 16; ++s) {
        int m = s * 16 + lane;
        const float4* xm4 = (const float4*)&tile[m * ROWSTRIDE];
        float bb[18];
        *(float4*)&bb[0]  = xm4[0];
        *(float4*)&bb[4]  = xm4[1];
        *(float4*)&bb[8]  = xm4[2];
        *(float4*)&bb[12] = xm4[3];
        *(float2*)&bb[16] = *(const float2*)&tile[m * ROWSTRIDE + 16];
        float acc = 0.f;
#pragma unroll
        for (int d = 0; d < 18; ++d) acc = fmaf(xr[d], bb[d], acc);
        k[s] = (mono32(acc) & 0xFFFFFF00u) | (unsigned)(255 - m);
    }

    // bitonic sort ascending (registers, fully unrolled)
#pragma unroll
    for (int kk = 2; kk <= 16; kk <<= 1) {
#pragma unroll
        for (int jj = kk >> 1; jj > 0; jj >>= 1) {
#pragma unroll
            for (int ii = 0; ii < 16; ++ii) {
                int ll = ii ^ jj;
                if (ll > ii) {
                    bool up = ((ii & kk) == 0);
                    unsigned a = k[ii], bbv = k[ll];
                    bool sw = up ? (a > bbv) : (a < bbv);
                    k[ii] = sw ? bbv : a; k[ll] = sw ? a : bbv;
                }
            }
        }
    }
#pragma unroll
    for (int s = 0; s < 16; ++s) kv[tid * 17 + s] = k[s];  // own-list only, no sync needed

    // 16-lane merge: extract global top-16 (lane e holds e-th largest in mycand)
    int ptr = 15;
    unsigned mycand = 0;
    unsigned myhead = k[15];
#pragma unroll
    for (int e = 0; e < 16; ++e) {
        unsigned W = myhead;
        unsigned o;
        o = __shfl_xor(W, 1);  W = (o > W) ? o : W;
        o = __shfl_xor(W, 2);  W = (o > W) ? o : W;
        o = __shfl_xor(W, 4);  W = (o > W) ? o : W;
        o = __shfl_xor(W, 8);  W = (o > W) ? o : W;
        if (lane == e) mycand = W;
        bool won = (myhead == W);
        ptr -= won ? 1 : 0;
        int rp = ptr < 0 ? 0 : ptr;
        unsigned reread = kv[tid * 17 + rp];
        myhead = won ? reread : myhead;
    }

    // certification: fp64 top-15 set == fp32 top-15 set unless boundary gap too small
    unsigned v15 = __shfl(mycand, 14, 16);
    unsigned v16 = __shfl(mycand, 15, 16);
    float lo = demono32(v15 & 0xFFFFFF00u) - 1e-5f;
    float hi = demono32((v16 & 0xFFFFFF00u) + 0x100u) + 1e-5f;
    bool dirty = !(hi < lo);
    if (lane == 0 && dirty) {
        unsigned slot = atomicAdd(dirtyCount, 1u);
        dirtyList[slot] = row;
    }

    // weights from fp32 sims (clean rows; dirty rows overwritten by K2b)
    int mym = 255 - (int)(mycand & 0xFFu);
    float sv = demono32(mycand & 0xFFFFFF00u);
    float alpha = ea[0], beta = eb[0];
    float sg = 1.f / (1.f + expf(-(beta + alpha * sv)));
    float v = (lane < KSEL) ? sg : -1e30f;
    float mx = v, of;
    of = __shfl_xor(mx, 1); mx = fmaxf(mx, of);
    of = __shfl_xor(mx, 2); mx = fmaxf(mx, of);
    of = __shfl_xor(mx, 4); mx = fmaxf(mx, of);
    of = __shfl_xor(mx, 8); mx = fmaxf(mx, of);
    float ex = expf(v - mx);
    float sm = ex;
    of = __shfl_xor(sm, 1); sm += of;
    of = __shfl_xor(sm, 2); sm += of;
    of = __shfl_xor(sm, 4); sm += of;
    of = __shfl_xor(sm, 8); sm += of;

    topi[row * 16 + lane] = mym;
    wkout[row * 16 + lane] = (lane < KSEL) ? (ex / sm) : 0.f;
}

// ---------------- K2b: exact fp64 redo for dirty rows (persistent, wave per row) ----------------
__global__ __launch_bounds__(64) void k2b_dirty(
    const double* __restrict__ xa64, const float* __restrict__ ea, const float* __restrict__ eb,
    const unsigned* __restrict__ dirtyCount, const int* __restrict__ dirtyList,
    int* __restrict__ topi, float* __restrict__ wkout)
{
    const int nd = (int)*dirtyCount;
    const int lane = threadIdx.x;
    for (int idx = blockIdx.x; idx < nd; idx += gridDim.x) {
        const int row = dirtyList[idx];
        const int p = row >> 8;
        const double* xr64 = xa64 + (size_t)row * ROWSTRIDE;

        double sv[4]; int smi[4];
#pragma unroll
        for (int s4 = 0; s4 < 4; ++s4) {
            int m = s4 * 64 + lane;
            const double* xm64 = xa64 + ((size_t)p * NN + m) * ROWSTRIDE;
            double s = 0.0;
#pragma unroll
            for (int d = 0; d < 18; ++d) s = fma(xr64[d], xm64[d], s);
            sv[s4] = s; smi[s4] = m;
        }

        double cv = -3.0; int cm = 0;
#pragma unroll
        for (int e = 0; e < KSEL; ++e) {
            double lv = sv[0]; int lm = smi[0];
#pragma unroll
            for (int s4 = 1; s4 < 4; ++s4) {
                bool t = (sv[s4] > lv) || (sv[s4] == lv && smi[s4] < lm);
                lv = t ? sv[s4] : lv; lm = t ? smi[s4] : lm;
            }
#pragma unroll
            for (int off = 1; off < 64; off <<= 1) {
                double ov = __shfl_xor(lv, off);
                int    om = __shfl_xor(lm, off);
                bool t = (ov > lv) || (ov == lv && om < lm);
                lv = t ? ov : lv; lm = t ? om : lm;
            }
            if (lane == e) { cv = lv; cm = lm; }
#pragma unroll
            for (int s4 = 0; s4 < 4; ++s4) if (smi[s4] == lm) sv[s4] = -3.0;
        }

        float alpha = ea[0], beta = eb[0];
        float sg = 1.f / (1.f + expf(-(beta + alpha * (float)cv)));
        float v = (lane < KSEL) ? sg : -1e30f;
        float mx = v, of;
        for (int off = 1; off < 64; off <<= 1) { of = __shfl_xor(mx, off); mx = fmaxf(mx, of); }
        float ex = expf(v - mx);
        float sm = ex;
        for (int off = 1; off < 64; off <<= 1) { of = __shfl_xor(sm, off); sm += of; }
        float w = ex / sm;
        if (lane < 16) {
            topi[row * 16 + lane] = (lane < KSEL) ? cm : 0;
            wkout[row * 16 + lane] = (lane < KSEL) ? w : 0.f;
        }
    }
}

// ---------------- K3: weighted gather-aggregate ----------------
__global__ __launch_bounds__(256) void k3_aggregate(
    const float* __restrict__ x, const int* __restrict__ topi, const float* __restrict__ wk,
    float* __restrict__ out)
{
    __shared__ float tile[NN * ROWSTRIDE];   // [pos][20], 16 channels used
    const int tid = threadIdx.x;
    const int pb = blockIdx.x >> 3, cg = blockIdx.x & 7, c0 = cg * 16;
    const int b = pb / 49, g = pb % 49;
    const int gI = g / 7, gJ = g % 7;
    const float* xb = x + ((size_t)b * CIN + c0) * PLANE + (size_t)(gI * 16 * HH + gJ * 16);

#pragma unroll
    for (int rep = 0; rep < 4; ++rep) {
        int linear = rep * 256 + tid;
        int cc = linear >> 6, chunk = linear & 63;
        int pos = chunk * 4, ii = pos >> 4, jj = pos & 15;
        float4 v = *(const float4*)(xb + (size_t)cc * PLANE + ii * HH + jj);
        tile[(pos + 0) * ROWSTRIDE + cc] = v.x;
        tile[(pos + 1) * ROWSTRIDE + cc] = v.y;
        tile[(pos + 2) * ROWSTRIDE + cc] = v.z;
        tile[(pos + 3) * ROWSTRIDE + cc] = v.w;
    }
    __syncthreads();

    const int n = tid;
    const int row = pb * NN + n;
    float acc[16];
#pragma unroll
    for (int c = 0; c < 16; ++c) acc[c] = 0.f;

#pragma unroll
    for (int kq = 0; kq < 4; ++kq) {
        int4   mi4 = ((const int4*)(topi + (size_t)row * 16))[kq];
        float4 w4  = ((const float4*)(wk  + (size_t)row * 16))[kq];
        const int   mis[4] = { mi4.x, mi4.y, mi4.z, mi4.w };
        const float ws4[4] = { w4.x, w4.y, w4.z, w4.w };
#pragma unroll
        for (int u = 0; u < 4; ++u) {
            float w = ws4[u];
            const float4* sp = (const float4*)&tile[mis[u] * ROWSTRIDE];
#pragma unroll
            for (int q = 0; q < 4; ++q) {
                float4 f = sp[q];
                acc[q * 4 + 0] = fmaf(w, f.x, acc[q * 4 + 0]);
                acc[q * 4 + 1] = fmaf(w, f.y, acc[q * 4 + 1]);
                acc[q * 4 + 2] = fmaf(w, f.z, acc[q * 4 + 2]);
                acc[q * 4 + 3] = fmaf(w, f.w, acc[q * 4 + 3]);
            }
        }
    }
    const int ii = n >> 4, jj = n & 15;
    float* ob = out + ((size_t)b * CIN + c0) * PLANE + (size_t)(gI * 16 * HH + gJ * 16) + ii * HH + jj;
#pragma unroll
    for (int cc = 0; cc < 16; ++cc) ob[(size_t)cc * PLANE] = acc[cc];
}

extern "C" void kernel_launch(void* const* d_in, const int* in_sizes, int n_in,
                              void* d_out, int out_size, void* d_ws, size_t ws_size,
                              hipStream_t stream) {
    const float* x  = (const float*)d_in[0];
    const float* fw = (const float*)d_in[1];
    const float* fb = (const float*)d_in[2];
    const float* ea = (const float*)d_in[3];
    const float* eb = (const float*)d_in[4];
    float* out = (float*)d_out;

    int nB = in_sizes[0] / (CIN * PLANE);   // 4
    int nP = nB * 49;                       // 196
    size_t nRows = (size_t)nP * NN;         // 50176

    char* wsb = (char*)d_ws;
    size_t off = 0;
    auto carve = [&](size_t bytes) { char* r = wsb + off; off = (off + bytes + 255) & ~(size_t)255; return r; };
    double*   xa64   = (double*)  carve(nRows * ROWSTRIDE * sizeof(double));
    float*    xa32   = (float*)   carve(nRows * ROWSTRIDE * sizeof(float));
    int*      topi   = (int*)     carve(nRows * 16 * sizeof(int));
    float*    wk     = (float*)   carve(nRows * 16 * sizeof(float));
    unsigned* dcnt   = (unsigned*)carve(256);
    int*      dlist  = (int*)     carve(nRows * sizeof(int));

    hipLaunchKernelGGL(k1_features, dim3(nP * 4), dim3(256), 0, stream, x, fw, fb, xa64, xa32, dcnt);
    hipLaunchKernelGGL(k2_select,   dim3(nP * 16), dim3(256), 0, stream, xa32, ea, eb, topi, wk, dcnt, dlist);
    hipLaunchKernelGGL(k2b_dirty,   dim3(256), dim3(64), 0, stream, xa64, ea, eb, dcnt, dlist, topi, wk);
    hipLaunchKernelGGL(k3_aggregate, dim3(nP * 8), dim3(256), 0, stream, x, topi, wk, out);
}